// Round 17
// baseline (378.628 us; speedup 1.0000x reference)
//
#include <hip/hip_runtime.h>
#include <math.h>

// LSTMLightweight on MI355X (R17 = R15 two-chain structure + 512-VGPR budget).
//   x[B,T,1] -> linear_in(1->16)+ReLU -> LSTM0(16) -> LSTM1(16) -> fc(16->8)+ReLU -> fc(8->1)
// Ledger: R12/R14/R16 all ~1900 cyc/step (VALU 36%, Mfma 9%) -> ~55% dependency
// stall in one resident wave. R15 (2 chains = 4 independent streams) was the
// right structure but its 4 live acc sets (64 regs) + state hit the 128-VGPR
// tier -> demotion -> full serialization (378us).
// R17 pulls the one untried knob: __launch_bounds__(64, 1) = min 1 wave/EU =
// 512-VGPR cap (m08: no spill through 450). Grid is latency-bound at 0.25-0.5
// waves/SIMD anyway, so a fat wave is free. With ~170 honest pressure << 512,
// all 4 streams stay resident and in-order issue can overlap ch1's MFMAs with
// ch0's combine stalls.
// Math identical to R12..R16 (absmax 2e-3): K-permuted A so B is lane-local
// (k=8g+i -> W_ih[.][4g+i] | W_hh[.][4g+i-4]; D row=4*(lane>>4)+q, col=lane&15),
// split-bf16 3-product MFMA, bias in C-init.

#define L2E 1.4426950408889634f
#define EPB 32        // elements per wave = 2 chains x 16 (MFMA N)

typedef short bf16x8 __attribute__((ext_vector_type(8)));
typedef float f32x4  __attribute__((ext_vector_type(4)));
typedef int   i32x4  __attribute__((ext_vector_type(4)));

__device__ __forceinline__ float sigm(float v) {
    return __builtin_amdgcn_rcpf(1.0f + __builtin_amdgcn_exp2f(-L2E * v));
}
__device__ __forceinline__ float tanh_(float v) {
    // tanh(v) = 1 - 2/(exp(2v)+1); saturates correctly at +-inf
    return 1.0f - 2.0f * __builtin_amdgcn_rcpf(1.0f + __builtin_amdgcn_exp2f((2.0f * L2E) * v));
}
// bf16 split helpers (truncation split: hi = top 16 bits; lo = bf16(v - hi))
__device__ __forceinline__ float hif(float a) {
    return __uint_as_float(__float_as_uint(a) & 0xFFFF0000u);
}
__device__ __forceinline__ unsigned pk2hi(float a, float b) {
    return (__float_as_uint(a) >> 16) | (__float_as_uint(b) & 0xFFFF0000u);
}
__device__ __forceinline__ unsigned pk2lo(float a, float b) {
    const float ra = a - hif(a), rb = b - hif(b);
    return (__float_as_uint(ra) >> 16) | (__float_as_uint(rb) & 0xFFFF0000u);
}
__device__ __forceinline__ short bhi(float a) { return (short)(__float_as_uint(a) >> 16); }
__device__ __forceinline__ bf16x8 mkfrag(unsigned w0, unsigned w1, unsigned w2, unsigned w3) {
    i32x4 t = {(int)w0, (int)w1, (int)w2, (int)w3};
    return __builtin_bit_cast(bf16x8, t);
}

// one layer's gate MFMAs: acc[m] = bias[m] + split-bf16(A)·B
#define GATES(ACC, AHI, ALO, BIAS, BH, BL)                                             \
    _Pragma("unroll")                                                                  \
    for (int m = 0; m < 4; ++m) {                                                      \
        ACC[m] = BIAS[m];                                                              \
        ACC[m] = __builtin_amdgcn_mfma_f32_16x16x32_bf16(ALO[m], BH, ACC[m], 0, 0, 0); \
        ACC[m] = __builtin_amdgcn_mfma_f32_16x16x32_bf16(AHI[m], BL, ACC[m], 0, 0, 0); \
        ACC[m] = __builtin_amdgcn_mfma_f32_16x16x32_bf16(AHI[m], BH, ACC[m], 0, 0, 0); \
    }

// combine: i,f,g,o -> c,h (per q); writes HV[4] and updates CC[4]
#define COMBINE(ACC, CC, HV)                                                           \
    _Pragma("unroll")                                                                  \
    for (int q = 0; q < 4; ++q) {                                                      \
        const float ig_ = sigm(ACC[0][q]);                                             \
        const float fg_ = sigm(ACC[1][q]);                                             \
        const float gv_ = tanh_(ACC[2][q]);                                            \
        const float og_ = sigm(ACC[3][q]);                                             \
        CC[q] = fmaf(fg_, CC[q], ig_ * gv_);                                           \
        HV[q] = og_ * tanh_(CC[q]);                                                    \
    }

__global__ __launch_bounds__(64, 1) void lstm_fat(
    const float* __restrict__ x,
    const float* __restrict__ w_in, const float* __restrict__ b_in,
    const float* __restrict__ w_ih0, const float* __restrict__ w_hh0,
    const float* __restrict__ b_ih0, const float* __restrict__ b_hh0,
    const float* __restrict__ w_ih1, const float* __restrict__ w_hh1,
    const float* __restrict__ b_ih1, const float* __restrict__ b_hh1,
    const float* __restrict__ fc_h_w, const float* __restrict__ fc_h_b,
    const float* __restrict__ fc_o_w, const float* __restrict__ fc_o_b,
    float* __restrict__ out, int B, int T)
{
    const int lane = threadIdx.x;        // 0..63
    const int e    = lane & 15;          // element column (= A row within tile)
    const int g    = lane >> 4;          // k-group / D-row group
    const int base = blockIdx.x * EPB;

    __shared__ float htab[EPB][16];      // head exchange only

    // ---- A-fragments (shared by both chains), K-permuted, split bf16 ----
    bf16x8 a0hi[4], a0lo[4], a1hi[4], a1lo[4];
    f32x4  bias0[4], bias1[4];
    #pragma unroll
    for (int m = 0; m < 4; ++m) {
        const int r = 16 * m + e;
        #pragma unroll
        for (int i = 0; i < 8; ++i) {
            const float w0 = (i < 4) ? w_ih0[r * 16 + 4 * g + i]
                                     : w_hh0[r * 16 + 4 * g + (i - 4)];
            const float w1 = (i < 4) ? w_ih1[r * 16 + 4 * g + i]
                                     : w_hh1[r * 16 + 4 * g + (i - 4)];
            a0hi[m][i] = bhi(w0);  a0lo[m][i] = bhi(w0 - hif(w0));
            a1hi[m][i] = bhi(w1);  a1lo[m][i] = bhi(w1 - hif(w1));
        }
        const int rd = 16 * m + 4 * g;
        #pragma unroll
        for (int q = 0; q < 4; ++q) {
            bias0[m][q] = b_ih0[rd + q] + b_hh0[rd + q];
            bias1[m][q] = b_ih1[rd + q] + b_hh1[rd + q];
        }
    }
    float winq[4], binq[4];
    #pragma unroll
    for (int q = 0; q < 4; ++q) { winq[q] = w_in[4 * g + q]; binq[q] = b_in[4 * g + q]; }

    // ---- per-chain state (fully unrolled -> registers) ----
    float c0[2][4], c1[2][4], h1v[2][4];
    unsigned h0p[2][4];                  // h0(t) packs: hi0,hi1,lo0,lo1
    unsigned h1p[2][4];                  // h1(t-1) packs
    const float* xrow[2];
    float xv1[2];
    #pragma unroll
    for (int ch = 0; ch < 2; ++ch) {
        int r = base + 16 * ch + e; if (r >= B) r = B - 1;
        xrow[ch] = x + (size_t)r * T;
        #pragma unroll
        for (int q = 0; q < 4; ++q) {
            c0[ch][q] = 0.f; c1[ch][q] = 0.f; h1v[ch][q] = 0.f;
            h0p[ch][q] = 0u; h1p[ch][q] = 0u;
        }
    }

    // ---- prologue: L0 at t=0 for both chains (h0_{-1}=0) ----
    #pragma unroll
    for (int ch = 0; ch < 2; ++ch) {
        const float xv = xrow[ch][0];
        float xq[4];
        #pragma unroll
        for (int q = 0; q < 4; ++q) xq[q] = fmaxf(fmaf(xv, winq[q], binq[q]), 0.0f);
        const bf16x8 Bh = mkfrag(pk2hi(xq[0], xq[1]), pk2hi(xq[2], xq[3]), 0u, 0u);
        const bf16x8 Bl = mkfrag(pk2lo(xq[0], xq[1]), pk2lo(xq[2], xq[3]), 0u, 0u);
        f32x4 acc[4];
        GATES(acc, a0hi, a0lo, bias0, Bh, Bl);
        float h0v[4];
        COMBINE(acc, c0[ch], h0v);
        h0p[ch][0] = pk2hi(h0v[0], h0v[1]); h0p[ch][1] = pk2hi(h0v[2], h0v[3]);
        h0p[ch][2] = pk2lo(h0v[0], h0v[1]); h0p[ch][3] = pk2lo(h0v[2], h0v[3]);
        xv1[ch] = xrow[ch][(T > 1) ? 1 : 0];
    }

    // ---- steady state: iteration t = { L1(t) || L0(t+1) } x { ch0, ch1 } ----
    for (int t = 0; t < T - 1; ++t) {
        const int tn = (t + 2 < T) ? (t + 2) : (T - 1);
        float xn[2];
        #pragma unroll
        for (int ch = 0; ch < 2; ++ch) xn[ch] = xrow[ch][tn];   // prefetch x(t+2)

        // build all B-frags first (from pre-update packs)
        bf16x8 B0h[2], B0l[2], B1h[2], B1l[2];
        #pragma unroll
        for (int ch = 0; ch < 2; ++ch) {
            float xq[4];
            #pragma unroll
            for (int q = 0; q < 4; ++q)
                xq[q] = fmaxf(fmaf(xv1[ch], winq[q], binq[q]), 0.0f);
            B0h[ch] = mkfrag(pk2hi(xq[0], xq[1]), pk2hi(xq[2], xq[3]),
                             h0p[ch][0], h0p[ch][1]);
            B0l[ch] = mkfrag(pk2lo(xq[0], xq[1]), pk2lo(xq[2], xq[3]),
                             h0p[ch][2], h0p[ch][3]);
            B1h[ch] = mkfrag(h0p[ch][0], h0p[ch][1], h1p[ch][0], h1p[ch][1]);
            B1l[ch] = mkfrag(h0p[ch][2], h0p[ch][3], h1p[ch][2], h1p[ch][3]);
        }

        // issue all 4 independent MFMA streams back-to-back
        f32x4 acc0[2][4], acc1[2][4];
        GATES(acc0[0], a0hi, a0lo, bias0, B0h[0], B0l[0]);   // ch0 L0(t+1)
        GATES(acc1[0], a1hi, a1lo, bias1, B1h[0], B1l[0]);   // ch0 L1(t)
        GATES(acc0[1], a0hi, a0lo, bias0, B0h[1], B0l[1]);   // ch1 L0(t+1)
        GATES(acc1[1], a1hi, a1lo, bias1, B1h[1], B1l[1]);   // ch1 L1(t)

        // combines: 4 independent streams interleave on VALU/trans pipes
        float h0v[2][4];
        COMBINE(acc0[0], c0[0], h0v[0]);
        COMBINE(acc1[0], c1[0], h1v[0]);
        COMBINE(acc0[1], c0[1], h0v[1]);
        COMBINE(acc1[1], c1[1], h1v[1]);

        #pragma unroll
        for (int ch = 0; ch < 2; ++ch) {
            h0p[ch][0] = pk2hi(h0v[ch][0], h0v[ch][1]);
            h0p[ch][1] = pk2hi(h0v[ch][2], h0v[ch][3]);
            h0p[ch][2] = pk2lo(h0v[ch][0], h0v[ch][1]);
            h0p[ch][3] = pk2lo(h0v[ch][2], h0v[ch][3]);
            h1p[ch][0] = pk2hi(h1v[ch][0], h1v[ch][1]);
            h1p[ch][1] = pk2hi(h1v[ch][2], h1v[ch][3]);
            h1p[ch][2] = pk2lo(h1v[ch][0], h1v[ch][1]);
            h1p[ch][3] = pk2lo(h1v[ch][2], h1v[ch][3]);
            xv1[ch] = xn[ch];
        }
    }

    // ---- epilogue: L1(T-1) for both chains ----
    #pragma unroll
    for (int ch = 0; ch < 2; ++ch) {
        const bf16x8 Bh = mkfrag(h0p[ch][0], h0p[ch][1], h1p[ch][0], h1p[ch][1]);
        const bf16x8 Bl = mkfrag(h0p[ch][2], h0p[ch][3], h1p[ch][2], h1p[ch][3]);
        f32x4 acc[4];
        GATES(acc, a1hi, a1lo, bias1, Bh, Bl);
        COMBINE(acc, c1[ch], h1v[ch]);
        *(float4*)&htab[16 * ch + e][4 * g] =
            make_float4(h1v[ch][0], h1v[ch][1], h1v[ch][2], h1v[ch][3]);
    }

    // ---- head: fc_h (16->8) + ReLU, fc_o (8->1) ----
    __syncthreads();
    if (lane < EPB) {
        const int ee = lane;
        float hv[16];
        #pragma unroll
        for (int k = 0; k < 16; ++k) hv[k] = htab[ee][k];
        float z[8];
        #pragma unroll
        for (int p = 0; p < 8; ++p) {
            float acc = fc_h_b[p];
            #pragma unroll
            for (int k = 0; k < 16; ++k) acc = fmaf(fc_h_w[p * 16 + k], hv[k], acc);
            z[p] = fmaxf(acc, 0.0f);
        }
        float o = fc_o_b[0];
        #pragma unroll
        for (int p = 0; p < 8; ++p) o = fmaf(fc_o_w[p], z[p], o);
        if (base + ee < B) out[base + ee] = o;
    }
}

extern "C" void kernel_launch(void* const* d_in, const int* in_sizes, int n_in,
                              void* d_out, int out_size, void* d_ws, size_t ws_size,
                              hipStream_t stream) {
    const float* x      = (const float*)d_in[0];
    const float* w_in   = (const float*)d_in[1];
    const float* b_in   = (const float*)d_in[2];
    const float* w_ih0  = (const float*)d_in[3];
    const float* w_hh0  = (const float*)d_in[4];
    const float* b_ih0  = (const float*)d_in[5];
    const float* b_hh0  = (const float*)d_in[6];
    const float* w_ih1  = (const float*)d_in[7];
    const float* w_hh1  = (const float*)d_in[8];
    const float* b_ih1  = (const float*)d_in[9];
    const float* b_hh1  = (const float*)d_in[10];
    const float* fc_h_w = (const float*)d_in[11];
    const float* fc_h_b = (const float*)d_in[12];
    const float* fc_o_w = (const float*)d_in[13];
    const float* fc_o_b = (const float*)d_in[14];

    const int B = out_size;                 // x is [B,T,1]
    const int T = in_sizes[0] / (B > 0 ? B : 1);
    const int grid = (B + EPB - 1) / EPB;   // 256 blocks at B=8192

    hipLaunchKernelGGL(lstm_fat, dim3(grid), dim3(64), 0, stream,
                       x, w_in, b_in, w_ih0, w_hh0, b_ih0, b_hh0,
                       w_ih1, w_hh1, b_ih1, b_hh1, fc_h_w, fc_h_b,
                       fc_o_w, fc_o_b, (float*)d_out, B, T);
}

// Round 18
// 323.286 us; speedup vs baseline: 1.1712x; 1.1712x over previous
//
#include <hip/hip_runtime.h>
#include <math.h>

// LSTMLightweight on MI355X (R18 = R14 + transcendental-free packed activations).
//   x[B,T,1] -> linear_in(1->16)+ReLU -> LSTM0(16) -> LSTM1(16) -> fc(16->8)+ReLU -> fc(8->1)
// Ledger: R17 proved the 128-arch-VGPR tier is immovable (launch_bounds(64,1)
// still pinned 128) -> >128-reg ILP paths closed. Issue model of R14's 1900
// cyc/step closes ONLY if v_exp/v_rcp cost ~16 cyc each (wave64, narrow trans
// unit): 80 trans/step x 16 = 1280 cyc ~= measured VALU busy. So the kernel is
// TRANS-ISSUE-bound.
// R18 removes every v_exp/v_rcp: sigmoid/tanh computed FMA-only on the packed
// f32 pipe (2 evals/instr): exp2 = magic-round + deg-4 Horner + int exponent
// add; rcp = bit-trick estimate + 2 packed Newton (rel err ~1e-5, negligible
// vs the 2e-3 bf16-split floor). Everything else identical to R14.
// Math: K-permuted A so B is lane-local (k=8g+i -> W_ih[.][4g+i] |
// W_hh[.][4g+i-4]; D row=4*(lane>>4)+q, col=lane&15), split-bf16 3-product
// MFMA, bias in C-init.

#define L2E 1.4426950408889634f
#define EPB 16        // elements per wave (= MFMA N)

typedef short bf16x8 __attribute__((ext_vector_type(8)));
typedef float f32x4  __attribute__((ext_vector_type(4)));
typedef int   i32x4  __attribute__((ext_vector_type(4)));
typedef float v2f    __attribute__((ext_vector_type(2)));

// ---------- packed FMA-only activations (no v_exp / v_rcp) ----------
__device__ __forceinline__ v2f pkc(float k) { return (v2f){k, k}; }

// 2^t for both halves; t clamped to +-120. Magic-round exact at -O3 (no
// -ffast-math -> no reassociation of (t+M)-M).
__device__ __forceinline__ v2f exp2_pk(v2f t) {
    t = __builtin_elementwise_min(__builtin_elementwise_max(t, pkc(-120.f)), pkc(120.f));
    const v2f magic = pkc(12582912.0f);            // 1.5 * 2^23
    const v2f fn = t + magic;                      // n encoded in mantissa
    const v2f fi = fn - magic;                     // round-to-nearest(t)
    const v2f f  = t - fi;                         // f in [-0.5, 0.5]
    v2f p = pkc(0.0089893397f);
    p = __builtin_elementwise_fma(p, f, pkc(0.0558282587f));
    p = __builtin_elementwise_fma(p, f, pkc(0.2401595472f));
    p = __builtin_elementwise_fma(p, f, pkc(0.6931471806f));
    p = __builtin_elementwise_fma(p, f, pkc(1.0f));
    // scale by 2^n: (uint(fn)<<23) == n<<23 (mod 2^32); add to float bits
    v2f r;
    r[0] = __uint_as_float(__float_as_uint(p[0]) + (__float_as_uint(fn[0]) << 23));
    r[1] = __uint_as_float(__float_as_uint(p[1]) + (__float_as_uint(fn[1]) << 23));
    return r;
}
// 1/d for d > 0 (normal): bit-trick estimate + 2 Newton iterations
__device__ __forceinline__ v2f rcp_pk(v2f d) {
    v2f y;
    y[0] = __uint_as_float(0x7EF311C3u - __float_as_uint(d[0]));
    y[1] = __uint_as_float(0x7EF311C3u - __float_as_uint(d[1]));
    y = y * __builtin_elementwise_fma(-d, y, pkc(2.0f));
    y = y * __builtin_elementwise_fma(-d, y, pkc(2.0f));
    return y;
}
__device__ __forceinline__ v2f sigm_pk(v2f v) {
    const v2f e = exp2_pk(v * pkc(-L2E));
    return rcp_pk(e + pkc(1.0f));
}
__device__ __forceinline__ v2f tanh_pk(v2f v) {
    const v2f e = exp2_pk(v * pkc(-2.0f * L2E));
    const v2f s = rcp_pk(e + pkc(1.0f));
    return __builtin_elementwise_fma(pkc(2.0f), s, pkc(-1.0f));
}

// ---------- bf16 split helpers ----------
__device__ __forceinline__ float hif(float a) {
    return __uint_as_float(__float_as_uint(a) & 0xFFFF0000u);
}
__device__ __forceinline__ unsigned pk2hi(float a, float b) {
    return (__float_as_uint(a) >> 16) | (__float_as_uint(b) & 0xFFFF0000u);
}
__device__ __forceinline__ unsigned pk2lo(float a, float b) {
    const float ra = a - hif(a), rb = b - hif(b);
    return (__float_as_uint(ra) >> 16) | (__float_as_uint(rb) & 0xFFFF0000u);
}
__device__ __forceinline__ short bhi(float a) { return (short)(__float_as_uint(a) >> 16); }
__device__ __forceinline__ bf16x8 mkfrag(unsigned w0, unsigned w1, unsigned w2, unsigned w3) {
    i32x4 t = {(int)w0, (int)w1, (int)w2, (int)w3};
    return __builtin_bit_cast(bf16x8, t);
}

// one layer's gate MFMAs: acc[m] = bias[m] + split-bf16(A)·B
#define GATES(ACC, AHI, ALO, BIAS, BH, BL)                                             \
    _Pragma("unroll")                                                                  \
    for (int m = 0; m < 4; ++m) {                                                      \
        ACC[m] = BIAS[m];                                                              \
        ACC[m] = __builtin_amdgcn_mfma_f32_16x16x32_bf16(ALO[m], BH, ACC[m], 0, 0, 0); \
        ACC[m] = __builtin_amdgcn_mfma_f32_16x16x32_bf16(AHI[m], BL, ACC[m], 0, 0, 0); \
        ACC[m] = __builtin_amdgcn_mfma_f32_16x16x32_bf16(AHI[m], BH, ACC[m], 0, 0, 0); \
    }

// packed combine: gates (i,f,g,o from ACC[0..3]) + cell pairs CP[2] -> HV[4]
#define COMBINE_PK(ACC, CP, HV)                                                        \
    do {                                                                               \
        const v2f i01 = {ACC[0][0], ACC[0][1]}, i23 = {ACC[0][2], ACC[0][3]};          \
        const v2f f01 = {ACC[1][0], ACC[1][1]}, f23 = {ACC[1][2], ACC[1][3]};          \
        const v2f g01 = {ACC[2][0], ACC[2][1]}, g23 = {ACC[2][2], ACC[2][3]};          \
        const v2f o01 = {ACC[3][0], ACC[3][1]}, o23 = {ACC[3][2], ACC[3][3]};          \
        const v2f si01 = sigm_pk(i01), si23 = sigm_pk(i23);                            \
        const v2f sf01 = sigm_pk(f01), sf23 = sigm_pk(f23);                            \
        const v2f tg01 = tanh_pk(g01), tg23 = tanh_pk(g23);                            \
        const v2f so01 = sigm_pk(o01), so23 = sigm_pk(o23);                            \
        CP[0] = __builtin_elementwise_fma(sf01, CP[0], si01 * tg01);                   \
        CP[1] = __builtin_elementwise_fma(sf23, CP[1], si23 * tg23);                   \
        const v2f tc01 = tanh_pk(CP[0]), tc23 = tanh_pk(CP[1]);                        \
        const v2f h01 = so01 * tc01, h23 = so23 * tc23;                                \
        HV[0] = h01[0]; HV[1] = h01[1]; HV[2] = h23[0]; HV[3] = h23[1];                \
    } while (0)

__global__ __launch_bounds__(64) void lstm_fma(
    const float* __restrict__ x,
    const float* __restrict__ w_in, const float* __restrict__ b_in,
    const float* __restrict__ w_ih0, const float* __restrict__ w_hh0,
    const float* __restrict__ b_ih0, const float* __restrict__ b_hh0,
    const float* __restrict__ w_ih1, const float* __restrict__ w_hh1,
    const float* __restrict__ b_ih1, const float* __restrict__ b_hh1,
    const float* __restrict__ fc_h_w, const float* __restrict__ fc_h_b,
    const float* __restrict__ fc_o_w, const float* __restrict__ fc_o_b,
    float* __restrict__ out, int B, int T)
{
    const int lane = threadIdx.x;        // 0..63
    const int e    = lane & 15;          // element column (= A row within tile)
    const int g    = lane >> 4;          // k-group / D-row group
    const int base = blockIdx.x * EPB;
    int rowe = base + e; if (rowe >= B) rowe = B - 1;

    __shared__ float htab[EPB][16];      // head exchange only

    // ---- A-fragments, K-permuted, split bf16 (MFMA operands: AGPR-free) ----
    bf16x8 a0hi[4], a0lo[4], a1hi[4], a1lo[4];
    f32x4  bias0[4], bias1[4];
    #pragma unroll
    for (int m = 0; m < 4; ++m) {
        const int r = 16 * m + e;
        #pragma unroll
        for (int i = 0; i < 8; ++i) {
            const float w0 = (i < 4) ? w_ih0[r * 16 + 4 * g + i]
                                     : w_hh0[r * 16 + 4 * g + (i - 4)];
            const float w1 = (i < 4) ? w_ih1[r * 16 + 4 * g + i]
                                     : w_hh1[r * 16 + 4 * g + (i - 4)];
            a0hi[m][i] = bhi(w0);  a0lo[m][i] = bhi(w0 - hif(w0));
            a1hi[m][i] = bhi(w1);  a1lo[m][i] = bhi(w1 - hif(w1));
        }
        const int rd = 16 * m + 4 * g;
        #pragma unroll
        for (int q = 0; q < 4; ++q) {
            bias0[m][q] = b_ih0[rd + q] + b_hh0[rd + q];
            bias1[m][q] = b_ih1[rd + q] + b_hh1[rd + q];
        }
    }
    float winq[4], binq[4];
    #pragma unroll
    for (int q = 0; q < 4; ++q) { winq[q] = w_in[4 * g + q]; binq[q] = b_in[4 * g + q]; }

    // ---- state (cell state kept as pairs for the packed combine) ----
    v2f c0p[2] = {pkc(0.f), pkc(0.f)};
    v2f c1p[2] = {pkc(0.f), pkc(0.f)};
    float h1v[4] = {0.f, 0.f, 0.f, 0.f};
    unsigned h0h0, h0h1, h0l0, h0l1;                 // h0(t) packs
    unsigned h1h0 = 0u, h1h1 = 0u, h1l0 = 0u, h1l1 = 0u;   // h1(t-1) packs

    const float* xrow = x + (size_t)rowe * T;

    // ---- prologue: L0 at t=0 (h0_{-1}=0) ----
    {
        const float xv = xrow[0];
        float xq[4];
        #pragma unroll
        for (int q = 0; q < 4; ++q) xq[q] = fmaxf(fmaf(xv, winq[q], binq[q]), 0.0f);
        const bf16x8 Bh = mkfrag(pk2hi(xq[0], xq[1]), pk2hi(xq[2], xq[3]), 0u, 0u);
        const bf16x8 Bl = mkfrag(pk2lo(xq[0], xq[1]), pk2lo(xq[2], xq[3]), 0u, 0u);
        f32x4 acc[4];
        GATES(acc, a0hi, a0lo, bias0, Bh, Bl);
        float h0v[4];
        COMBINE_PK(acc, c0p, h0v);
        h0h0 = pk2hi(h0v[0], h0v[1]); h0h1 = pk2hi(h0v[2], h0v[3]);
        h0l0 = pk2lo(h0v[0], h0v[1]); h0l1 = pk2lo(h0v[2], h0v[3]);
    }

    float xv1 = xrow[(T > 1) ? 1 : 0];               // x(t+1) for the loop

    // ---- steady state: iteration t does L1(t) || L0(t+1) (independent) ----
    for (int t = 0; t < T - 1; ++t) {
        const int tn = (t + 2 < T) ? (t + 2) : (T - 1);
        const float xn = xrow[tn];                   // prefetch x(t+2)

        float xq[4];
        #pragma unroll
        for (int q = 0; q < 4; ++q) xq[q] = fmaxf(fmaf(xv1, winq[q], binq[q]), 0.0f);

        const bf16x8 B0h = mkfrag(pk2hi(xq[0], xq[1]), pk2hi(xq[2], xq[3]), h0h0, h0h1);
        const bf16x8 B0l = mkfrag(pk2lo(xq[0], xq[1]), pk2lo(xq[2], xq[3]), h0l0, h0l1);
        const bf16x8 B1h = mkfrag(h0h0, h0h1, h1h0, h1h1);
        const bf16x8 B1l = mkfrag(h0l0, h0l1, h1l0, h1l1);

        f32x4 acc0[4], acc1[4];
        GATES(acc0, a0hi, a0lo, bias0, B0h, B0l);    // L0(t+1)
        GATES(acc1, a1hi, a1lo, bias1, B1h, B1l);    // L1(t)

        float h0v[4];
        COMBINE_PK(acc0, c0p, h0v);                  // h0(t+1)
        COMBINE_PK(acc1, c1p, h1v);                  // h1(t)

        h0h0 = pk2hi(h0v[0], h0v[1]); h0h1 = pk2hi(h0v[2], h0v[3]);
        h0l0 = pk2lo(h0v[0], h0v[1]); h0l1 = pk2lo(h0v[2], h0v[3]);
        h1h0 = pk2hi(h1v[0], h1v[1]); h1h1 = pk2hi(h1v[2], h1v[3]);
        h1l0 = pk2lo(h1v[0], h1v[1]); h1l1 = pk2lo(h1v[2], h1v[3]);
        xv1 = xn;
    }

    // ---- epilogue: L1(T-1) from h0(T-1), h1(T-2) ----
    {
        const bf16x8 Bh = mkfrag(h0h0, h0h1, h1h0, h1h1);
        const bf16x8 Bl = mkfrag(h0l0, h0l1, h1l0, h1l1);
        f32x4 acc[4];
        GATES(acc, a1hi, a1lo, bias1, Bh, Bl);
        COMBINE_PK(acc, c1p, h1v);                   // final h1
    }

    // ---- head: fc_h (16->8) + ReLU, fc_o (8->1) ----
    *(float4*)&htab[e][4 * g] = make_float4(h1v[0], h1v[1], h1v[2], h1v[3]);
    __syncthreads();
    if (lane < EPB) {
        const int ee = lane;
        float hv[16];
        #pragma unroll
        for (int k = 0; k < 16; ++k) hv[k] = htab[ee][k];
        float z[8];
        #pragma unroll
        for (int p = 0; p < 8; ++p) {
            float acc = fc_h_b[p];
            #pragma unroll
            for (int k = 0; k < 16; ++k) acc = fmaf(fc_h_w[p * 16 + k], hv[k], acc);
            z[p] = fmaxf(acc, 0.0f);
        }
        float o = fc_o_b[0];
        #pragma unroll
        for (int p = 0; p < 8; ++p) o = fmaf(fc_o_w[p], z[p], o);
        if (base + ee < B) out[base + ee] = o;
    }
}

extern "C" void kernel_launch(void* const* d_in, const int* in_sizes, int n_in,
                              void* d_out, int out_size, void* d_ws, size_t ws_size,
                              hipStream_t stream) {
    const float* x      = (const float*)d_in[0];
    const float* w_in   = (const float*)d_in[1];
    const float* b_in   = (const float*)d_in[2];
    const float* w_ih0  = (const float*)d_in[3];
    const float* w_hh0  = (const float*)d_in[4];
    const float* b_ih0  = (const float*)d_in[5];
    const float* b_hh0  = (const float*)d_in[6];
    const float* w_ih1  = (const float*)d_in[7];
    const float* w_hh1  = (const float*)d_in[8];
    const float* b_ih1  = (const float*)d_in[9];
    const float* b_hh1  = (const float*)d_in[10];
    const float* fc_h_w = (const float*)d_in[11];
    const float* fc_h_b = (const float*)d_in[12];
    const float* fc_o_w = (const float*)d_in[13];
    const float* fc_o_b = (const float*)d_in[14];

    const int B = out_size;                 // x is [B,T,1]
    const int T = in_sizes[0] / (B > 0 ? B : 1);
    const int grid = (B + EPB - 1) / EPB;   // 512 blocks at B=8192

    hipLaunchKernelGGL(lstm_fma, dim3(grid), dim3(64), 0, stream,
                       x, w_in, b_in, w_ih0, w_hh0, b_ih0, b_hh0,
                       w_ih1, w_hh1, b_ih1, b_hh1, fc_h_w, fc_h_b,
                       fc_o_w, fc_o_b, (float*)d_out, B, T);
}